// Round 6
// baseline (923.022 us; speedup 1.0000x reference)
//
#include <hip/hip_runtime.h>

#define USER_NUM 100000
#define ITEM_NUM 50000
#define N_NODES  150000   // USER_NUM + ITEM_NUM
#define EMB_DIM  64
#define NNZ      4800000

#define NBANDS       8
#define ROWS_PER_XCD 18750                 // N_NODES / 8, also the col-band width
#define SCAN_N       (N_NODES * NBANDS)    // 1.2M buckets
#define SCAN_ITEMS   8192                  // per scan block: 256 thr x 32 items
#define NUM_SCAN_BLOCKS ((SCAN_N + SCAN_ITEMS - 1) / SCAN_ITEMS)  // 147

#define SLICE 8192                          // edges per scatter block-slice

// bf16 helpers: unpack a uint32 holding two bf16 (low ushort = even elem)
__device__ __forceinline__ float bflo(unsigned u) {
    return __uint_as_float(u << 16);
}
__device__ __forceinline__ float bfhi(unsigned u) {
    return __uint_as_float(u & 0xFFFF0000u);
}
// fp32 -> bf16 (RNE), returned in low 16 bits
__device__ __forceinline__ unsigned f2bf(float f) {
    unsigned u = __float_as_uint(f);
    return (u + 0x7FFFu + ((u >> 16) & 1u)) >> 16;
}

// ---------------------------------------------------------------------------
// init: acc (= d_out) = concat(user_emb, item_emb) fp32;
//       xb = same, packed bf16 (8 elems = uint4 per thread)
// ---------------------------------------------------------------------------
__global__ void lgcn_init(const float4* __restrict__ user,
                          const float4* __restrict__ item,
                          uint4* __restrict__ xb,
                          float4* __restrict__ acc) {
    int i = blockIdx.x * blockDim.x + threadIdx.x;   // chunk of 8 floats
    if (i >= N_NODES * 8) return;
    const int user_chunks = USER_NUM * 8;
    float4 f0, f1;
    if (i < user_chunks) {
        f0 = user[i * 2];
        f1 = user[i * 2 + 1];
    } else {
        f0 = item[(i - user_chunks) * 2];
        f1 = item[(i - user_chunks) * 2 + 1];
    }
    acc[i * 2]     = f0;
    acc[i * 2 + 1] = f1;
    uint4 p;
    p.x = f2bf(f0.x) | (f2bf(f0.y) << 16);
    p.y = f2bf(f0.z) | (f2bf(f0.w) << 16);
    p.z = f2bf(f1.x) | (f2bf(f1.y) << 16);
    p.w = f2bf(f1.z) | (f2bf(f1.w) << 16);
    xb[i] = p;
}

// ---------------------------------------------------------------------------
// bucket hist: key = row * 8 + col-band
// ---------------------------------------------------------------------------
__global__ void lgcn_hist(const int* __restrict__ row,
                          const int* __restrict__ col,
                          int* __restrict__ cnt) {
    int e = blockIdx.x * blockDim.x + threadIdx.x;
    if (e >= NNZ) return;
    int band = (int)((unsigned)col[e] / ROWS_PER_XCD);
    atomicAdd(&cnt[row[e] * NBANDS + band], 1);
}

// ---------------------------------------------------------------------------
// scan step a: per-block sums over 8192-element tiles (256 thr x 32 items)
// ---------------------------------------------------------------------------
__global__ void lgcn_scan_blocksums(const int* __restrict__ cnt,
                                    int* __restrict__ blockSum) {
    int b = blockIdx.x, t = threadIdx.x;
    int base = b * SCAN_ITEMS + t * 32;
    int s = 0;
    if (base < SCAN_N) {          // SCAN_N % 32 == 0: all-or-nothing per thread
#pragma unroll
        for (int k = 0; k < 32; k += 4) {
            int4 q = *(const int4*)&cnt[base + k];
            s += q.x + q.y + q.z + q.w;
        }
    }
    __shared__ int red[256];
    red[t] = s;
    __syncthreads();
    for (int off = 128; off > 0; off >>= 1) {
        if (t < off) red[t] += red[t + off];
        __syncthreads();
    }
    if (t == 0) blockSum[b] = red[0];
}

// ---------------------------------------------------------------------------
// scan step b: exclusive scan of block sums (single block)
// ---------------------------------------------------------------------------
__global__ void lgcn_scan_sums(const int* __restrict__ blockSum,
                               int* __restrict__ blockBase,
                               int* __restrict__ bptr) {
    int t = threadIdx.x;
    __shared__ int s[256];
    int v = (t < NUM_SCAN_BLOCKS) ? blockSum[t] : 0;
    s[t] = v;
    __syncthreads();
    for (int off = 1; off < 256; off <<= 1) {
        int x = (t >= off) ? s[t - off] : 0;
        __syncthreads();
        s[t] += x;
        __syncthreads();
    }
    if (t < NUM_SCAN_BLOCKS) blockBase[t] = s[t] - v;  // exclusive
    if (t == 0) bptr[SCAN_N] = NNZ;
}

// ---------------------------------------------------------------------------
// scan step c: final exclusive scan -> bptr[0..SCAN_N)
// ---------------------------------------------------------------------------
__global__ void lgcn_scan_final(const int* __restrict__ cnt,
                                const int* __restrict__ blockBase,
                                int* __restrict__ bptr) {
    int b = blockIdx.x, t = threadIdx.x;
    int base = b * SCAN_ITEMS + t * 32;
    int v[32];
    int tsum = 0;
    bool act = (base < SCAN_N);
    if (act) {
#pragma unroll
        for (int k = 0; k < 32; k += 4) {
            int4 q = *(const int4*)&cnt[base + k];
            v[k] = q.x; v[k + 1] = q.y; v[k + 2] = q.z; v[k + 3] = q.w;
            tsum += q.x + q.y + q.z + q.w;
        }
    }
    __shared__ int s[256];
    s[t] = tsum;
    __syncthreads();
    for (int off = 1; off < 256; off <<= 1) {
        int x = (t >= off) ? s[t - off] : 0;
        __syncthreads();
        s[t] += x;
        __syncthreads();
    }
    if (act) {
        int p = blockBase[b] + (s[t] - tsum);  // exclusive prefix
#pragma unroll
        for (int k = 0; k < 32; ++k) {
            bptr[base + k] = p;
            p += v[k];
        }
    }
}

// ---------------------------------------------------------------------------
// scatter, XCD-ownership filtered: block b owns row range [(b&7)*18750, +18750)
// and scans edge slice (b>>3). Each CSR region is written by one XCD only, so
// its lines stay L2-resident and collect sibling edges before writeback.
// ---------------------------------------------------------------------------
__global__ void lgcn_scatter(const int* __restrict__ row,
                             const int* __restrict__ col,
                             const float* __restrict__ vals,
                             const int* __restrict__ bptr,
                             int* __restrict__ cursor,
                             int2* __restrict__ csr_cv) {
    int b = blockIdx.x;
    int lo = (b & 7) * ROWS_PER_XCD;
    int e0 = (b >> 3) * SLICE + threadIdx.x;
    int e1 = (b >> 3) * SLICE + SLICE;
    if (e1 > NNZ) e1 = NNZ;
    for (int e = e0; e < e1; e += 256) {
        int r = row[e];
        if ((unsigned)(r - lo) < ROWS_PER_XCD) {
            int cl = col[e];
            int band = (int)((unsigned)cl / ROWS_PER_XCD);
            int key = r * NBANDS + band;
            int pos = bptr[key] + atomicAdd(&cursor[key], 1);
            csr_cv[pos] = make_int2(cl, __float_as_int(vals[e]));
        }
    }
}

// ---------------------------------------------------------------------------
// SpMM, bf16 gather: one wave per row. Lanes = 8 edge-subgroups x 8 chunks.
// Each lane loads 16B = 8 bf16 of x[col]; a row is 128B = ONE cache line.
// Edges are col-band-sorted within each row, so concurrent waves gather from
// a ~2.4MB moving window of x (L2-resident). fp32 accumulate; epilogue
// writes y as bf16 (next layer input) and folds fp32 y into acc.
// ---------------------------------------------------------------------------
__global__ __launch_bounds__(256) void lgcn_spmm_bf16(
    const int* __restrict__ bptr,
    const int2* __restrict__ csr_cv,
    const uint4* __restrict__ xb,
    uint4* __restrict__ yb,
    float4* __restrict__ acc,
    float scale) {
    int gid = blockIdx.x * blockDim.x + threadIdx.x;
    int r = gid >> 6;
    if (r >= N_NODES) return;
    int lane = threadIdx.x & 63;
    int c = lane & 7;        // which 16B chunk (8 bf16) of the 64-dim row
    int sub = lane >> 3;     // edge subgroup 0..7

    int start = bptr[r * NBANDS];
    int end = bptr[r * NBANDS + NBANDS];

    float a0[8] = {0.f, 0.f, 0.f, 0.f, 0.f, 0.f, 0.f, 0.f};
    float a1[8] = {0.f, 0.f, 0.f, 0.f, 0.f, 0.f, 0.f, 0.f};

    int e = start + sub;
    // main loop: 16 edges per wave iteration (2 per subgroup, independent)
    for (; e + 8 < end; e += 16) {
        int2 cv0 = csr_cv[e];
        int2 cv1 = csr_cv[e + 8];
        uint4 u0 = xb[cv0.x * 8 + c];
        uint4 u1 = xb[cv1.x * 8 + c];
        float v0 = __int_as_float(cv0.y);
        float v1 = __int_as_float(cv1.y);
        a0[0] += v0 * bflo(u0.x); a0[1] += v0 * bfhi(u0.x);
        a0[2] += v0 * bflo(u0.y); a0[3] += v0 * bfhi(u0.y);
        a0[4] += v0 * bflo(u0.z); a0[5] += v0 * bfhi(u0.z);
        a0[6] += v0 * bflo(u0.w); a0[7] += v0 * bfhi(u0.w);
        a1[0] += v1 * bflo(u1.x); a1[1] += v1 * bfhi(u1.x);
        a1[2] += v1 * bflo(u1.y); a1[3] += v1 * bfhi(u1.y);
        a1[4] += v1 * bflo(u1.z); a1[5] += v1 * bfhi(u1.z);
        a1[6] += v1 * bflo(u1.w); a1[7] += v1 * bfhi(u1.w);
    }
    // at most one edge left per subgroup
    if (e < end) {
        int2 cv = csr_cv[e];
        uint4 u = xb[cv.x * 8 + c];
        float v = __int_as_float(cv.y);
        a0[0] += v * bflo(u.x); a0[1] += v * bfhi(u.x);
        a0[2] += v * bflo(u.y); a0[3] += v * bfhi(u.y);
        a0[4] += v * bflo(u.z); a0[5] += v * bfhi(u.z);
        a0[6] += v * bflo(u.w); a0[7] += v * bfhi(u.w);
    }

    float a[8];
#pragma unroll
    for (int k = 0; k < 8; ++k) a[k] = a0[k] + a1[k];

    // reduce across the 8 edge subgroups (lanes differing in bits 3,4,5)
#pragma unroll
    for (int k = 0; k < 8; ++k) {
        a[k] += __shfl_xor(a[k], 8);
        a[k] += __shfl_xor(a[k], 16);
        a[k] += __shfl_xor(a[k], 32);
    }

    if (sub == 0) {
        // bf16 y for the next layer's gather
        uint4 p;
        p.x = f2bf(a[0]) | (f2bf(a[1]) << 16);
        p.y = f2bf(a[2]) | (f2bf(a[3]) << 16);
        p.z = f2bf(a[4]) | (f2bf(a[5]) << 16);
        p.w = f2bf(a[6]) | (f2bf(a[7]) << 16);
        yb[r * 8 + c] = p;
        // fp32 accumulator update (full-precision y folded in)
        int idx = r * 16 + c * 2;
        float4 o0 = acc[idx];
        float4 o1 = acc[idx + 1];
        o0.x = (o0.x + a[0]) * scale;
        o0.y = (o0.y + a[1]) * scale;
        o0.z = (o0.z + a[2]) * scale;
        o0.w = (o0.w + a[3]) * scale;
        o1.x = (o1.x + a[4]) * scale;
        o1.y = (o1.y + a[5]) * scale;
        o1.z = (o1.z + a[6]) * scale;
        o1.w = (o1.w + a[7]) * scale;
        acc[idx] = o0;
        acc[idx + 1] = o1;
    }
}

extern "C" void kernel_launch(void* const* d_in, const int* in_sizes, int n_in,
                              void* d_out, int out_size, void* d_ws, size_t ws_size,
                              hipStream_t stream) {
    const float* user_emb = (const float*)d_in[0];
    const float* item_emb = (const float*)d_in[1];
    const int*   adj_row  = (const int*)d_in[2];
    const int*   adj_col  = (const int*)d_in[3];
    const float* adj_vals = (const float*)d_in[4];
    float* out = (float*)d_out;

    // workspace layout (~86.5 MB total)
    uint4* xb_a  = (uint4*)d_ws;                               // 19.2 MB bf16
    uint4* xb_b  = xb_a + (size_t)N_NODES * 8;                 // 19.2 MB bf16
    int*   cnt   = (int*)(xb_b + (size_t)N_NODES * 8);         // 4.8 MB
    int*   bptr  = cnt + SCAN_N;                               // 4.8 MB
    int*   blockSum  = bptr + (SCAN_N + 1);                    // 1 KB
    int*   blockBase = blockSum + 256;                         // 1 KB
    int2*  csr_cv  = (int2*)(blockBase + 256);                 // 38.4 MB

    // init: xb_a = bf16(concat(user,item)); out (acc) = fp32 concat
    {
        int threads = 256;
        int blocks = (N_NODES * 8 + threads - 1) / threads;
        lgcn_init<<<blocks, threads, 0, stream>>>(
            (const float4*)user_emb, (const float4*)item_emb,
            xb_a, (float4*)out);
    }

    // ---- CSR build (buckets keyed by row*8 + col-band) ----
    hipMemsetAsync(cnt, 0, (size_t)SCAN_N * sizeof(int), stream);
    {
        int threads = 256;
        int blocks = (NNZ + threads - 1) / threads;
        lgcn_hist<<<blocks, threads, 0, stream>>>(adj_row, adj_col, cnt);
    }
    lgcn_scan_blocksums<<<NUM_SCAN_BLOCKS, 256, 0, stream>>>(cnt, blockSum);
    lgcn_scan_sums<<<1, 256, 0, stream>>>(blockSum, blockBase, bptr);
    lgcn_scan_final<<<NUM_SCAN_BLOCKS, 256, 0, stream>>>(cnt, blockBase, bptr);
    hipMemsetAsync(cnt, 0, (size_t)SCAN_N * sizeof(int), stream);  // reuse as cursor
    {
        int nslices = (NNZ + SLICE - 1) / SLICE;   // 586
        lgcn_scatter<<<nslices * 8, 256, 0, stream>>>(
            adj_row, adj_col, adj_vals, bptr, cnt, csr_cv);
    }

    // ---- 3 propagation layers (bf16-gather SpMM, fused fp32 acc update) ----
    const int spmm_block = 256;                       // 4 waves = 4 rows / block
    const int spmm_grid = (N_NODES * 64 + spmm_block - 1) / spmm_block;
    for (int layer = 0; layer < 3; ++layer) {
        float scale = (layer == 2) ? 0.25f : 1.0f;
        lgcn_spmm_bf16<<<spmm_grid, spmm_block, 0, stream>>>(
            bptr, csr_cv, xb_a, xb_b, (float4*)out, scale);
        uint4* t = xb_a; xb_a = xb_b; xb_b = t;
    }
}

// Round 7
// 843.425 us; speedup vs baseline: 1.0944x; 1.0944x over previous
//
#include <hip/hip_runtime.h>

#define USER_NUM 100000
#define ITEM_NUM 50000
#define N_NODES  150000   // USER_NUM + ITEM_NUM
#define EMB_DIM  64
#define NNZ      4800000

#define ROWS_PER_BUCKET 512
#define NBUCK ((N_NODES + ROWS_PER_BUCKET - 1) / ROWS_PER_BUCKET)  // 293
#define TILE 8192
#define NTILES ((NNZ + TILE - 1) / TILE)  // 586

#define SCAN_ITEMS 1024
#define NUM_SCAN_BLOCKS ((N_NODES + SCAN_ITEMS - 1) / SCAN_ITEMS)  // 147

// bf16 helpers: unpack a uint32 holding two bf16 (low ushort = even elem)
__device__ __forceinline__ float bflo(unsigned u) {
    return __uint_as_float(u << 16);
}
__device__ __forceinline__ float bfhi(unsigned u) {
    return __uint_as_float(u & 0xFFFF0000u);
}
// fp32 -> bf16 (RNE), returned in low 16 bits
__device__ __forceinline__ unsigned f2bf(float f) {
    unsigned u = __float_as_uint(f);
    return (u + 0x7FFFu + ((u >> 16) & 1u)) >> 16;
}

// ---------------------------------------------------------------------------
// init: acc (= d_out) = concat(user_emb, item_emb) fp32;
//       xb = same, packed bf16 (8 elems = uint4 per thread)
// ---------------------------------------------------------------------------
__global__ void lgcn_init(const float4* __restrict__ user,
                          const float4* __restrict__ item,
                          uint4* __restrict__ xb,
                          float4* __restrict__ acc) {
    int i = blockIdx.x * blockDim.x + threadIdx.x;   // chunk of 8 floats
    if (i >= N_NODES * 8) return;
    const int user_chunks = USER_NUM * 8;
    float4 f0, f1;
    if (i < user_chunks) {
        f0 = user[i * 2];
        f1 = user[i * 2 + 1];
    } else {
        f0 = item[(i - user_chunks) * 2];
        f1 = item[(i - user_chunks) * 2 + 1];
    }
    acc[i * 2]     = f0;
    acc[i * 2 + 1] = f1;
    uint4 p;
    p.x = f2bf(f0.x) | (f2bf(f0.y) << 16);
    p.y = f2bf(f0.z) | (f2bf(f0.w) << 16);
    p.z = f2bf(f1.x) | (f2bf(f1.y) << 16);
    p.w = f2bf(f1.z) | (f2bf(f1.w) << 16);
    xb[i] = p;
}

// ---------------------------------------------------------------------------
// per-row histogram
// ---------------------------------------------------------------------------
__global__ void lgcn_hist(const int* __restrict__ row, int* __restrict__ cnt) {
    int e = blockIdx.x * blockDim.x + threadIdx.x;
    if (e >= NNZ) return;
    atomicAdd(&cnt[row[e]], 1);
}

// ---------------------------------------------------------------------------
// scan step a: per-block sums of cnt (1024 elements / block)
// ---------------------------------------------------------------------------
__global__ void lgcn_scan_blocksums(const int* __restrict__ cnt,
                                    int* __restrict__ blockSum) {
    int b = blockIdx.x, t = threadIdx.x;
    int base = b * SCAN_ITEMS + t * 4;
    int s = 0;
#pragma unroll
    for (int k = 0; k < 4; ++k) {
        int i = base + k;
        if (i < N_NODES) s += cnt[i];
    }
    __shared__ int red[256];
    red[t] = s;
    __syncthreads();
    for (int off = 128; off > 0; off >>= 1) {
        if (t < off) red[t] += red[t + off];
        __syncthreads();
    }
    if (t == 0) blockSum[b] = red[0];
}

// ---------------------------------------------------------------------------
// scan step b: exclusive scan of block sums (single block)
// ---------------------------------------------------------------------------
__global__ void lgcn_scan_sums(const int* __restrict__ blockSum,
                               int* __restrict__ blockBase,
                               int* __restrict__ row_ptr) {
    int t = threadIdx.x;
    __shared__ int s[256];
    int v = (t < NUM_SCAN_BLOCKS) ? blockSum[t] : 0;
    s[t] = v;
    __syncthreads();
    for (int off = 1; off < 256; off <<= 1) {
        int x = (t >= off) ? s[t - off] : 0;
        __syncthreads();
        s[t] += x;
        __syncthreads();
    }
    if (t < NUM_SCAN_BLOCKS) blockBase[t] = s[t] - v;  // exclusive
    if (t == 0) row_ptr[N_NODES] = NNZ;
}

// ---------------------------------------------------------------------------
// scan step c: final exclusive scan -> row_ptr[0..N_NODES)
// ---------------------------------------------------------------------------
__global__ void lgcn_scan_final(const int* __restrict__ cnt,
                                const int* __restrict__ blockBase,
                                int* __restrict__ row_ptr) {
    int b = blockIdx.x, t = threadIdx.x;
    int base = b * SCAN_ITEMS + t * 4;
    int v[4];
    int tsum = 0;
#pragma unroll
    for (int k = 0; k < 4; ++k) {
        int i = base + k;
        v[k] = (i < N_NODES) ? cnt[i] : 0;
        tsum += v[k];
    }
    __shared__ int s[256];
    s[t] = tsum;
    __syncthreads();
    for (int off = 1; off < 256; off <<= 1) {
        int x = (t >= off) ? s[t - off] : 0;
        __syncthreads();
        s[t] += x;
        __syncthreads();
    }
    int p = blockBase[b] + (s[t] - tsum);  // exclusive prefix
#pragma unroll
    for (int k = 0; k < 4; ++k) {
        int i = base + k;
        if (i < N_NODES) row_ptr[i] = p;
        p += v[k];
    }
}

// ---------------------------------------------------------------------------
// bucket cursor init: bucket b's region starts at row_ptr[b*512]
// ---------------------------------------------------------------------------
__global__ void lgcn_bcur_init(const int* __restrict__ row_ptr,
                               int* __restrict__ bucket_cursor) {
    int b = blockIdx.x * blockDim.x + threadIdx.x;
    if (b < NBUCK) bucket_cursor[b] = row_ptr[b * ROWS_PER_BUCKET];
}

// ---------------------------------------------------------------------------
// partition pass 1: tile of 8192 edges per block. LDS histogram over 293
// row-buckets, ONE global atomicAdd per bucket per block reserves a
// contiguous run (~28 edges = ~224B); edges written into the run. Sibling
// bytes of each output line are written by one block within a short window,
// so L2 assembles full lines before writeback.
// ---------------------------------------------------------------------------
__global__ __launch_bounds__(256) void lgcn_partition(
    const int* __restrict__ row,
    const int* __restrict__ col,
    const float* __restrict__ vals,
    int* __restrict__ bucket_cursor,
    unsigned short* __restrict__ t_rlo,
    int2* __restrict__ t_cv) {
    __shared__ int hist[NBUCK];
    __shared__ int cur[NBUCK];
    int tid = threadIdx.x;
    int tileStart = blockIdx.x * TILE;
    int tileEnd = tileStart + TILE;
    if (tileEnd > NNZ) tileEnd = NNZ;

    for (int b = tid; b < NBUCK; b += 256) hist[b] = 0;
    __syncthreads();

    int rows_[32];
#pragma unroll
    for (int k = 0; k < 32; ++k) {
        int e = tileStart + tid + k * 256;
        int r = -1;
        if (e < tileEnd) {
            r = row[e];
            atomicAdd(&hist[r >> 9], 1);
        }
        rows_[k] = r;
    }
    __syncthreads();
    for (int b = tid; b < NBUCK; b += 256)
        cur[b] = atomicAdd(&bucket_cursor[b], hist[b]);
    __syncthreads();
#pragma unroll
    for (int k = 0; k < 32; ++k) {
        int e = tileStart + tid + k * 256;
        if (e < tileEnd) {
            int r = rows_[k];
            int pos = atomicAdd(&cur[r >> 9], 1);
            t_rlo[pos] = (unsigned short)(r & 511);
            t_cv[pos] = make_int2(col[e], __float_as_int(vals[e]));
        }
    }
}

// ---------------------------------------------------------------------------
// partition pass 2: one block per bucket. Per-row cursors live in LDS (no
// global atomics); reads the bucket's contiguous ~131KB segment and writes
// final CSR positions confined to the same window -> L2-resident, full-line
// writebacks.
// ---------------------------------------------------------------------------
__global__ __launch_bounds__(256) void lgcn_bucket_scatter(
    const int* __restrict__ row_ptr,
    const unsigned short* __restrict__ t_rlo,
    const int2* __restrict__ t_cv,
    int2* __restrict__ csr_cv) {
    __shared__ int cur[ROWS_PER_BUCKET];
    int b = blockIdx.x;
    int lo = b * ROWS_PER_BUCKET;
    int hi = lo + ROWS_PER_BUCKET;
    if (hi > N_NODES) hi = N_NODES;
    for (int i = threadIdx.x; i < hi - lo; i += 256)
        cur[i] = row_ptr[lo + i];
    __syncthreads();
    int start = row_ptr[lo];
    int end = row_ptr[hi];
    for (int e = start + threadIdx.x; e < end; e += 256) {
        int rl = t_rlo[e];
        int2 cv = t_cv[e];
        int pos = atomicAdd(&cur[rl], 1);
        csr_cv[pos] = cv;
    }
}

// ---------------------------------------------------------------------------
// SpMM, bf16 gather: one wave per row. Lanes = 8 edge-subgroups x 8 chunks.
// Each lane loads 16B = 8 bf16 of x[col]; a row is 128B = ONE cache line.
// fp32 accumulate; epilogue writes y as bf16 (next layer input) and folds
// fp32 y into acc: acc = (acc + y) * scale.
// ---------------------------------------------------------------------------
__global__ __launch_bounds__(256) void lgcn_spmm_bf16(
    const int* __restrict__ row_ptr,
    const int2* __restrict__ csr_cv,
    const uint4* __restrict__ xb,
    uint4* __restrict__ yb,
    float4* __restrict__ acc,
    float scale) {
    int gid = blockIdx.x * blockDim.x + threadIdx.x;
    int r = gid >> 6;
    if (r >= N_NODES) return;
    int lane = threadIdx.x & 63;
    int c = lane & 7;        // which 16B chunk (8 bf16) of the 64-dim row
    int sub = lane >> 3;     // edge subgroup 0..7

    int start = row_ptr[r];
    int end = row_ptr[r + 1];

    float a0[8] = {0.f, 0.f, 0.f, 0.f, 0.f, 0.f, 0.f, 0.f};
    float a1[8] = {0.f, 0.f, 0.f, 0.f, 0.f, 0.f, 0.f, 0.f};

    int e = start + sub;
    // main loop: 16 edges per wave iteration (2 per subgroup, independent)
    for (; e + 8 < end; e += 16) {
        int2 cv0 = csr_cv[e];
        int2 cv1 = csr_cv[e + 8];
        uint4 u0 = xb[cv0.x * 8 + c];
        uint4 u1 = xb[cv1.x * 8 + c];
        float v0 = __int_as_float(cv0.y);
        float v1 = __int_as_float(cv1.y);
        a0[0] += v0 * bflo(u0.x); a0[1] += v0 * bfhi(u0.x);
        a0[2] += v0 * bflo(u0.y); a0[3] += v0 * bfhi(u0.y);
        a0[4] += v0 * bflo(u0.z); a0[5] += v0 * bfhi(u0.z);
        a0[6] += v0 * bflo(u0.w); a0[7] += v0 * bfhi(u0.w);
        a1[0] += v1 * bflo(u1.x); a1[1] += v1 * bfhi(u1.x);
        a1[2] += v1 * bflo(u1.y); a1[3] += v1 * bfhi(u1.y);
        a1[4] += v1 * bflo(u1.z); a1[5] += v1 * bfhi(u1.z);
        a1[6] += v1 * bflo(u1.w); a1[7] += v1 * bfhi(u1.w);
    }
    // at most one edge left per subgroup
    if (e < end) {
        int2 cv = csr_cv[e];
        uint4 u = xb[cv.x * 8 + c];
        float v = __int_as_float(cv.y);
        a0[0] += v * bflo(u.x); a0[1] += v * bfhi(u.x);
        a0[2] += v * bflo(u.y); a0[3] += v * bfhi(u.y);
        a0[4] += v * bflo(u.z); a0[5] += v * bfhi(u.z);
        a0[6] += v * bflo(u.w); a0[7] += v * bfhi(u.w);
    }

    float a[8];
#pragma unroll
    for (int k = 0; k < 8; ++k) a[k] = a0[k] + a1[k];

    // reduce across the 8 edge subgroups (lanes differing in bits 3,4,5)
#pragma unroll
    for (int k = 0; k < 8; ++k) {
        a[k] += __shfl_xor(a[k], 8);
        a[k] += __shfl_xor(a[k], 16);
        a[k] += __shfl_xor(a[k], 32);
    }

    if (sub == 0) {
        // bf16 y for the next layer's gather
        uint4 p;
        p.x = f2bf(a[0]) | (f2bf(a[1]) << 16);
        p.y = f2bf(a[2]) | (f2bf(a[3]) << 16);
        p.z = f2bf(a[4]) | (f2bf(a[5]) << 16);
        p.w = f2bf(a[6]) | (f2bf(a[7]) << 16);
        yb[r * 8 + c] = p;
        // fp32 accumulator update (full-precision y folded in)
        int idx = r * 16 + c * 2;
        float4 o0 = acc[idx];
        float4 o1 = acc[idx + 1];
        o0.x = (o0.x + a[0]) * scale;
        o0.y = (o0.y + a[1]) * scale;
        o0.z = (o0.z + a[2]) * scale;
        o0.w = (o0.w + a[3]) * scale;
        o1.x = (o1.x + a[4]) * scale;
        o1.y = (o1.y + a[5]) * scale;
        o1.z = (o1.z + a[6]) * scale;
        o1.w = (o1.w + a[7]) * scale;
        acc[idx] = o0;
        acc[idx + 1] = o1;
    }
}

extern "C" void kernel_launch(void* const* d_in, const int* in_sizes, int n_in,
                              void* d_out, int out_size, void* d_ws, size_t ws_size,
                              hipStream_t stream) {
    const float* user_emb = (const float*)d_in[0];
    const float* item_emb = (const float*)d_in[1];
    const int*   adj_row  = (const int*)d_in[2];
    const int*   adj_col  = (const int*)d_in[3];
    const float* adj_vals = (const float*)d_in[4];
    float* out = (float*)d_out;

    // workspace layout (~107 MB total):
    //   xb_a (19.2MB) | csr_cv (38.4MB) | S (48MB union) | cnt/row_ptr/small
    // S holds {t_cv 38.4MB + t_rlo 9.6MB} during CSR build, then xb_b (19.2MB)
    // during the layers (t_* are dead before layer-0 spmm writes xb_b).
    char* base = (char*)d_ws;
    uint4* xb_a   = (uint4*)base;                              // 19.2 MB
    int2*  csr_cv = (int2*)(base + 19200000);                  // 38.4 MB
    char*  S      = base + 57600000;
    int2*  t_cv   = (int2*)S;                                  // 38.4 MB
    unsigned short* t_rlo = (unsigned short*)(S + 38400000);   // 9.6 MB
    uint4* xb_b   = (uint4*)S;                                 // aliases t_cv
    int*   cnt    = (int*)(S + 48000000);                      // 600 KB
    int*   row_ptr = cnt + N_NODES;                            // 600 KB
    int*   blockSum  = row_ptr + (N_NODES + 1);
    int*   blockBase = blockSum + 256;
    int*   bucket_cursor = blockBase + 256;                    // 293 ints

    // init: xb_a = bf16(concat(user,item)); out (acc) = fp32 concat
    {
        int threads = 256;
        int blocks = (N_NODES * 8 + threads - 1) / threads;
        lgcn_init<<<blocks, threads, 0, stream>>>(
            (const float4*)user_emb, (const float4*)item_emb,
            xb_a, (float4*)out);
    }

    // ---- CSR build ----
    hipMemsetAsync(cnt, 0, (size_t)N_NODES * sizeof(int), stream);
    {
        int threads = 256;
        int blocks = (NNZ + threads - 1) / threads;
        lgcn_hist<<<blocks, threads, 0, stream>>>(adj_row, cnt);
    }
    lgcn_scan_blocksums<<<NUM_SCAN_BLOCKS, 256, 0, stream>>>(cnt, blockSum);
    lgcn_scan_sums<<<1, 256, 0, stream>>>(blockSum, blockBase, row_ptr);
    lgcn_scan_final<<<NUM_SCAN_BLOCKS, 256, 0, stream>>>(cnt, blockBase, row_ptr);
    lgcn_bcur_init<<<(NBUCK + 255) / 256, 256, 0, stream>>>(row_ptr, bucket_cursor);
    lgcn_partition<<<NTILES, 256, 0, stream>>>(
        adj_row, adj_col, adj_vals, bucket_cursor, t_rlo, t_cv);
    lgcn_bucket_scatter<<<NBUCK, 256, 0, stream>>>(
        row_ptr, t_rlo, t_cv, csr_cv);

    // ---- 3 propagation layers (bf16-gather SpMM, fused fp32 acc update) ----
    const int spmm_block = 256;                       // 4 waves = 4 rows / block
    const int spmm_grid = (N_NODES * 64 + spmm_block - 1) / spmm_block;
    uint4* xa = xb_a;
    uint4* xbv = xb_b;
    for (int layer = 0; layer < 3; ++layer) {
        float scale = (layer == 2) ? 0.25f : 1.0f;
        lgcn_spmm_bf16<<<spmm_grid, spmm_block, 0, stream>>>(
            row_ptr, csr_cv, xa, xbv, (float4*)out, scale);
        uint4* t = xa; xa = xbv; xbv = t;
    }
}

// Round 8
// 732.030 us; speedup vs baseline: 1.2609x; 1.1522x over previous
//
#include <hip/hip_runtime.h>

#define USER_NUM 100000
#define ITEM_NUM 50000
#define N_NODES  150000   // USER_NUM + ITEM_NUM
#define EMB_DIM  64
#define NNZ      4800000

#define ROWS_PER_BUCKET 256
#define NBUCK ((N_NODES + ROWS_PER_BUCKET - 1) / ROWS_PER_BUCKET)  // 586
#define BUCK_CAP 9216            // expected 8192 edges/bucket, +11 sigma slack
#define TILE 8192
#define NTILES ((NNZ + TILE - 1) / TILE)  // 586
#define EPT 32                   // edges per thread in partition

#define SCAN_ITEMS 1024
#define NUM_SCAN_BLOCKS ((N_NODES + SCAN_ITEMS - 1) / SCAN_ITEMS)  // 147

// bf16 helpers: unpack a uint32 holding two bf16 (low ushort = even elem)
__device__ __forceinline__ float bflo(unsigned u) {
    return __uint_as_float(u << 16);
}
__device__ __forceinline__ float bfhi(unsigned u) {
    return __uint_as_float(u & 0xFFFF0000u);
}
// fp32 -> bf16 (RNE), returned in low 16 bits
__device__ __forceinline__ unsigned f2bf(float f) {
    unsigned u = __float_as_uint(f);
    return (u + 0x7FFFu + ((u >> 16) & 1u)) >> 16;
}

// ---------------------------------------------------------------------------
// init: acc (= d_out) = concat(user_emb, item_emb) fp32;
//       xb = same, packed bf16 (8 elems = uint4 per thread)
// ---------------------------------------------------------------------------
__global__ void lgcn_init(const float4* __restrict__ user,
                          const float4* __restrict__ item,
                          uint4* __restrict__ xb,
                          float4* __restrict__ acc) {
    int i = blockIdx.x * blockDim.x + threadIdx.x;   // chunk of 8 floats
    if (i >= N_NODES * 8) return;
    const int user_chunks = USER_NUM * 8;
    float4 f0, f1;
    if (i < user_chunks) {
        f0 = user[i * 2];
        f1 = user[i * 2 + 1];
    } else {
        f0 = item[(i - user_chunks) * 2];
        f1 = item[(i - user_chunks) * 2 + 1];
    }
    acc[i * 2]     = f0;
    acc[i * 2 + 1] = f1;
    uint4 p;
    p.x = f2bf(f0.x) | (f2bf(f0.y) << 16);
    p.y = f2bf(f0.z) | (f2bf(f0.w) << 16);
    p.z = f2bf(f1.x) | (f2bf(f1.y) << 16);
    p.w = f2bf(f1.z) | (f2bf(f1.w) << 16);
    xb[i] = p;
}

// ---------------------------------------------------------------------------
// bucket cursor init: bucket b's staging region starts at b*BUCK_CAP
// ---------------------------------------------------------------------------
__global__ void lgcn_bcur_init(int* __restrict__ bucket_cursor) {
    int b = blockIdx.x * blockDim.x + threadIdx.x;
    if (b < NBUCK) bucket_cursor[b] = b * BUCK_CAP;
}

// ---------------------------------------------------------------------------
// partition (pass 1, fused per-row hist): per 8192-edge tile, do a full
// in-LDS counting sort by row-bucket, then write out in SORTED SLOT ORDER so
// consecutive threads store to consecutive global addresses — sector/line
// assembly happens inside each wave's store instructions, independent of L2
// dirty-line lifetime (R7's 4.8x write amplification). One global atomicAdd
// per (block, bucket) reserves the run; lslot packs (bucket, row&255, le).
// ---------------------------------------------------------------------------
__global__ __launch_bounds__(256) void lgcn_partition(
    const int* __restrict__ row,
    const int* __restrict__ col,
    const float* __restrict__ vals,
    int* __restrict__ cnt,            // per-row global histogram (pre-zeroed)
    int* __restrict__ bucket_cursor,  // pre-init to b*BUCK_CAP
    unsigned char* __restrict__ t_rlo,
    int2* __restrict__ t_cv) {
    __shared__ int hist[NBUCK];
    __shared__ int excl[NBUCK];       // localstart, then running local cursor
    __shared__ int delta[NBUCK];      // global pos = delta[b] + slot
    __shared__ unsigned lslot[TILE];
    __shared__ int sscan[256];

    int tid = threadIdx.x;
    int tileStart = blockIdx.x * TILE;
    int tileCount = NNZ - tileStart;
    if (tileCount > TILE) tileCount = TILE;

    for (int b = tid; b < NBUCK; b += 256) hist[b] = 0;
    __syncthreads();

    // phase A: LDS bucket hist + global per-row hist; cache rows in regs
    int rws[EPT];
#pragma unroll
    for (int k = 0; k < EPT; ++k) {
        int le = tid + k * 256;
        int r = -1;
        if (le < tileCount) {
            r = row[tileStart + le];
            atomicAdd(&hist[r >> 8], 1);
            atomicAdd(&cnt[r], 1);
        }
        rws[k] = r;
    }
    __syncthreads();

    // phase B: exclusive scan of hist (thread t owns 3 consecutive buckets)
    int base3 = tid * 3;
    int h0 = (base3 < NBUCK) ? hist[base3] : 0;
    int h1 = (base3 + 1 < NBUCK) ? hist[base3 + 1] : 0;
    int h2 = (base3 + 2 < NBUCK) ? hist[base3 + 2] : 0;
    int tsum = h0 + h1 + h2;
    sscan[tid] = tsum;
    __syncthreads();
    for (int off = 1; off < 256; off <<= 1) {
        int x = (tid >= off) ? sscan[tid - off] : 0;
        __syncthreads();
        sscan[tid] += x;
        __syncthreads();
    }
    {
        int p = sscan[tid] - tsum;
        if (base3 < NBUCK)     { excl[base3]     = p; p += h0; }
        if (base3 + 1 < NBUCK) { excl[base3 + 1] = p; p += h1; }
        if (base3 + 2 < NBUCK) { excl[base3 + 2] = p; p += h2; }
    }
    __syncthreads();

    // reserve global runs; delta maps local slot -> global position
    for (int b = tid; b < NBUCK; b += 256) {
        int c = hist[b];
        int rb = c ? atomicAdd(&bucket_cursor[b], c) : 0;
        delta[b] = rb - excl[b];
    }
    __syncthreads();

    // phase C: place edges into bucket-sorted local slots
    // pack: bucket (b<2048) << 21 | (row&255) << 13 | le (<8192)
#pragma unroll
    for (int k = 0; k < EPT; ++k) {
        int le = tid + k * 256;
        if (le < tileCount) {
            int r = rws[k];
            int b = r >> 8;
            int lp = atomicAdd(&excl[b], 1);
            lslot[lp] = ((unsigned)b << 21) | ((unsigned)(r & 255) << 13) |
                        (unsigned)le;
        }
    }
    __syncthreads();

    // phase D: write out in slot order -> coalesced per-run bursts
    for (int i = tid; i < tileCount; i += 256) {
        unsigned s = lslot[i];
        int b = s >> 21;
        int rlo = (s >> 13) & 255;
        int le = s & 8191;
        int e = tileStart + le;
        int gpos = delta[b] + i;
        if (gpos < (b + 1) * BUCK_CAP) {   // overflow guard, statistically never
            t_rlo[gpos] = (unsigned char)rlo;
            t_cv[gpos] = make_int2(col[e], __float_as_int(vals[e]));
        }
    }
}

// ---------------------------------------------------------------------------
// scan step a: per-block sums of cnt (1024 elements / block)
// ---------------------------------------------------------------------------
__global__ void lgcn_scan_blocksums(const int* __restrict__ cnt,
                                    int* __restrict__ blockSum) {
    int b = blockIdx.x, t = threadIdx.x;
    int base = b * SCAN_ITEMS + t * 4;
    int s = 0;
#pragma unroll
    for (int k = 0; k < 4; ++k) {
        int i = base + k;
        if (i < N_NODES) s += cnt[i];
    }
    __shared__ int red[256];
    red[t] = s;
    __syncthreads();
    for (int off = 128; off > 0; off >>= 1) {
        if (t < off) red[t] += red[t + off];
        __syncthreads();
    }
    if (t == 0) blockSum[b] = red[0];
}

// ---------------------------------------------------------------------------
// scan step b: exclusive scan of block sums (single block)
// ---------------------------------------------------------------------------
__global__ void lgcn_scan_sums(const int* __restrict__ blockSum,
                               int* __restrict__ blockBase,
                               int* __restrict__ row_ptr) {
    int t = threadIdx.x;
    __shared__ int s[256];
    int v = (t < NUM_SCAN_BLOCKS) ? blockSum[t] : 0;
    s[t] = v;
    __syncthreads();
    for (int off = 1; off < 256; off <<= 1) {
        int x = (t >= off) ? s[t - off] : 0;
        __syncthreads();
        s[t] += x;
        __syncthreads();
    }
    if (t < NUM_SCAN_BLOCKS) blockBase[t] = s[t] - v;  // exclusive
    if (t == 0) row_ptr[N_NODES] = NNZ;
}

// ---------------------------------------------------------------------------
// scan step c: final exclusive scan -> row_ptr[0..N_NODES)
// ---------------------------------------------------------------------------
__global__ void lgcn_scan_final(const int* __restrict__ cnt,
                                const int* __restrict__ blockBase,
                                int* __restrict__ row_ptr) {
    int b = blockIdx.x, t = threadIdx.x;
    int base = b * SCAN_ITEMS + t * 4;
    int v[4];
    int tsum = 0;
#pragma unroll
    for (int k = 0; k < 4; ++k) {
        int i = base + k;
        v[k] = (i < N_NODES) ? cnt[i] : 0;
        tsum += v[k];
    }
    __shared__ int s[256];
    s[t] = tsum;
    __syncthreads();
    for (int off = 1; off < 256; off <<= 1) {
        int x = (t >= off) ? s[t - off] : 0;
        __syncthreads();
        s[t] += x;
        __syncthreads();
    }
    int p = blockBase[b] + (s[t] - tsum);  // exclusive prefix
#pragma unroll
    for (int k = 0; k < 4; ++k) {
        int i = base + k;
        if (i < N_NODES) row_ptr[i] = p;
        p += v[k];
    }
}

// ---------------------------------------------------------------------------
// pass 2: one block per bucket (586 blocks). Per-row cursors in LDS; reads
// the bucket's contiguous staging segment (<=72KB) and writes final CSR
// positions confined to a ~65KB window -> L2-resident, full-line writebacks.
// ---------------------------------------------------------------------------
__global__ __launch_bounds__(256) void lgcn_bucket_scatter(
    const int* __restrict__ row_ptr,
    const int* __restrict__ bucket_cursor,
    const unsigned char* __restrict__ t_rlo,
    const int2* __restrict__ t_cv,
    int2* __restrict__ csr_cv) {
    __shared__ int cur[ROWS_PER_BUCKET];
    int b = blockIdx.x;
    int lo = b * ROWS_PER_BUCKET;
    int nrows = N_NODES - lo;
    if (nrows > ROWS_PER_BUCKET) nrows = ROWS_PER_BUCKET;
    for (int i = threadIdx.x; i < nrows; i += 256)
        cur[i] = row_ptr[lo + i];
    __syncthreads();
    int base = b * BUCK_CAP;
    int count = bucket_cursor[b] - base;
    if (count > BUCK_CAP) count = BUCK_CAP;
    for (int e = base + threadIdx.x; e < base + count; e += 256) {
        int rl = t_rlo[e];
        int2 cv = t_cv[e];
        int pos = atomicAdd(&cur[rl], 1);
        csr_cv[pos] = cv;
    }
}

// ---------------------------------------------------------------------------
// SpMM, bf16 gather: one wave per row. Lanes = 8 edge-subgroups x 8 chunks.
// Each lane loads 16B = 8 bf16 of x[col]; a row is 128B = ONE cache line.
// fp32 accumulate; epilogue writes y as bf16 (next layer input) and folds
// fp32 y into acc: acc = (acc + y) * scale.   (unchanged from R7)
// ---------------------------------------------------------------------------
__global__ __launch_bounds__(256) void lgcn_spmm_bf16(
    const int* __restrict__ row_ptr,
    const int2* __restrict__ csr_cv,
    const uint4* __restrict__ xb,
    uint4* __restrict__ yb,
    float4* __restrict__ acc,
    float scale) {
    int gid = blockIdx.x * blockDim.x + threadIdx.x;
    int r = gid >> 6;
    if (r >= N_NODES) return;
    int lane = threadIdx.x & 63;
    int c = lane & 7;        // which 16B chunk (8 bf16) of the 64-dim row
    int sub = lane >> 3;     // edge subgroup 0..7

    int start = row_ptr[r];
    int end = row_ptr[r + 1];

    float a0[8] = {0.f, 0.f, 0.f, 0.f, 0.f, 0.f, 0.f, 0.f};
    float a1[8] = {0.f, 0.f, 0.f, 0.f, 0.f, 0.f, 0.f, 0.f};

    int e = start + sub;
    // main loop: 16 edges per wave iteration (2 per subgroup, independent)
    for (; e + 8 < end; e += 16) {
        int2 cv0 = csr_cv[e];
        int2 cv1 = csr_cv[e + 8];
        uint4 u0 = xb[cv0.x * 8 + c];
        uint4 u1 = xb[cv1.x * 8 + c];
        float v0 = __int_as_float(cv0.y);
        float v1 = __int_as_float(cv1.y);
        a0[0] += v0 * bflo(u0.x); a0[1] += v0 * bfhi(u0.x);
        a0[2] += v0 * bflo(u0.y); a0[3] += v0 * bfhi(u0.y);
        a0[4] += v0 * bflo(u0.z); a0[5] += v0 * bfhi(u0.z);
        a0[6] += v0 * bflo(u0.w); a0[7] += v0 * bfhi(u0.w);
        a1[0] += v1 * bflo(u1.x); a1[1] += v1 * bfhi(u1.x);
        a1[2] += v1 * bflo(u1.y); a1[3] += v1 * bfhi(u1.y);
        a1[4] += v1 * bflo(u1.z); a1[5] += v1 * bfhi(u1.z);
        a1[6] += v1 * bflo(u1.w); a1[7] += v1 * bfhi(u1.w);
    }
    // at most one edge left per subgroup
    if (e < end) {
        int2 cv = csr_cv[e];
        uint4 u = xb[cv.x * 8 + c];
        float v = __int_as_float(cv.y);
        a0[0] += v * bflo(u.x); a0[1] += v * bfhi(u.x);
        a0[2] += v * bflo(u.y); a0[3] += v * bfhi(u.y);
        a0[4] += v * bflo(u.z); a0[5] += v * bfhi(u.z);
        a0[6] += v * bflo(u.w); a0[7] += v * bfhi(u.w);
    }

    float a[8];
#pragma unroll
    for (int k = 0; k < 8; ++k) a[k] = a0[k] + a1[k];

    // reduce across the 8 edge subgroups (lanes differing in bits 3,4,5)
#pragma unroll
    for (int k = 0; k < 8; ++k) {
        a[k] += __shfl_xor(a[k], 8);
        a[k] += __shfl_xor(a[k], 16);
        a[k] += __shfl_xor(a[k], 32);
    }

    if (sub == 0) {
        // bf16 y for the next layer's gather
        uint4 p;
        p.x = f2bf(a[0]) | (f2bf(a[1]) << 16);
        p.y = f2bf(a[2]) | (f2bf(a[3]) << 16);
        p.z = f2bf(a[4]) | (f2bf(a[5]) << 16);
        p.w = f2bf(a[6]) | (f2bf(a[7]) << 16);
        yb[r * 8 + c] = p;
        // fp32 accumulator update (full-precision y folded in)
        int idx = r * 16 + c * 2;
        float4 o0 = acc[idx];
        float4 o1 = acc[idx + 1];
        o0.x = (o0.x + a[0]) * scale;
        o0.y = (o0.y + a[1]) * scale;
        o0.z = (o0.z + a[2]) * scale;
        o0.w = (o0.w + a[3]) * scale;
        o1.x = (o1.x + a[4]) * scale;
        o1.y = (o1.y + a[5]) * scale;
        o1.z = (o1.z + a[6]) * scale;
        o1.w = (o1.w + a[7]) * scale;
        acc[idx] = o0;
        acc[idx + 1] = o1;
    }
}

extern "C" void kernel_launch(void* const* d_in, const int* in_sizes, int n_in,
                              void* d_out, int out_size, void* d_ws, size_t ws_size,
                              hipStream_t stream) {
    const float* user_emb = (const float*)d_in[0];
    const float* item_emb = (const float*)d_in[1];
    const int*   adj_row  = (const int*)d_in[2];
    const int*   adj_col  = (const int*)d_in[3];
    const float* adj_vals = (const float*)d_in[4];
    float* out = (float*)d_out;

    // workspace layout (~108 MB):
    //   xb_a (19.2MB) | csr_cv (38.4MB) | S (union): {t_cv 43.2MB + t_rlo
    //   5.4MB} during CSR build, xb_b (19.2MB) during layers | cnt | row_ptr
    char* base = (char*)d_ws;
    uint4* xb_a   = (uint4*)base;                               // 19.2 MB
    int2*  csr_cv = (int2*)(base + 19200000);                   // 38.4 MB
    char*  S      = base + 57600000;
    const size_t T_ENTRIES = (size_t)NBUCK * BUCK_CAP;          // 5,400,576
    int2*  t_cv   = (int2*)S;                                   // 43.2 MB
    unsigned char* t_rlo = (unsigned char*)(S + T_ENTRIES * 8); // 5.4 MB
    uint4* xb_b   = (uint4*)S;                                  // aliases t_cv
    char*  tail   = S + T_ENTRIES * 9 + (16 - (T_ENTRIES * 9) % 16) % 16;
    int*   cnt    = (int*)tail;                                 // 600 KB
    int*   row_ptr = cnt + N_NODES;                             // 600 KB
    int*   blockSum  = row_ptr + (N_NODES + 1);
    int*   blockBase = blockSum + 256;
    int*   bucket_cursor = blockBase + 256;                     // 586 ints

    // init: xb_a = bf16(concat(user,item)); out (acc) = fp32 concat
    {
        int threads = 256;
        int blocks = (N_NODES * 8 + threads - 1) / threads;
        lgcn_init<<<blocks, threads, 0, stream>>>(
            (const float4*)user_emb, (const float4*)item_emb,
            xb_a, (float4*)out);
    }

    // ---- CSR build ----
    hipMemsetAsync(cnt, 0, (size_t)N_NODES * sizeof(int), stream);
    lgcn_bcur_init<<<(NBUCK + 255) / 256, 256, 0, stream>>>(bucket_cursor);
    lgcn_partition<<<NTILES, 256, 0, stream>>>(
        adj_row, adj_col, adj_vals, cnt, bucket_cursor, t_rlo, t_cv);
    lgcn_scan_blocksums<<<NUM_SCAN_BLOCKS, 256, 0, stream>>>(cnt, blockSum);
    lgcn_scan_sums<<<1, 256, 0, stream>>>(blockSum, blockBase, row_ptr);
    lgcn_scan_final<<<NUM_SCAN_BLOCKS, 256, 0, stream>>>(cnt, blockBase, row_ptr);
    lgcn_bucket_scatter<<<NBUCK, 256, 0, stream>>>(
        row_ptr, bucket_cursor, t_rlo, t_cv, csr_cv);

    // ---- 3 propagation layers (bf16-gather SpMM, fused fp32 acc update) ----
    const int spmm_block = 256;                       // 4 waves = 4 rows / block
    const int spmm_grid = (N_NODES * 64 + spmm_block - 1) / spmm_block;
    uint4* xa = xb_a;
    uint4* xbv = xb_b;
    for (int layer = 0; layer < 3; ++layer) {
        float scale = (layer == 2) ? 0.25f : 1.0f;
        lgcn_spmm_bf16<<<spmm_grid, spmm_block, 0, stream>>>(
            row_ptr, csr_cv, xa, xbv, (float4*)out, scale);
        uint4* t = xa; xa = xbv; xbv = t;
    }
}

// Round 9
// 604.148 us; speedup vs baseline: 1.5278x; 1.2117x over previous
//
#include <hip/hip_runtime.h>

#define USER_NUM 100000
#define ITEM_NUM 50000
#define N_NODES  150000   // USER_NUM + ITEM_NUM
#define EMB_DIM  64
#define NNZ      4800000

#define CB_SHIFT 10
#define ROWS_PER_CB 1024
#define NCB ((N_NODES + ROWS_PER_CB - 1) / ROWS_PER_CB)   // 147
#define CB_CAP 34000            // expected 32.7k edges/bucket, ~7 sigma slack
#define TILE 8192
#define NTILES ((NNZ + TILE - 1) / TILE)  // 586
#define EPT 32                  // edges per thread in partition

#define SCAN_ITEMS 1024
#define NUM_SCAN_BLOCKS ((N_NODES + SCAN_ITEMS - 1) / SCAN_ITEMS)  // 147

// bf16 helpers: unpack a uint32 holding two bf16 (low ushort = even elem)
__device__ __forceinline__ float bflo(unsigned u) {
    return __uint_as_float(u << 16);
}
__device__ __forceinline__ float bfhi(unsigned u) {
    return __uint_as_float(u & 0xFFFF0000u);
}
// fp32 -> bf16 (RNE), returned in low 16 bits
__device__ __forceinline__ unsigned f2bf(float f) {
    unsigned u = __float_as_uint(f);
    return (u + 0x7FFFu + ((u >> 16) & 1u)) >> 16;
}

// ---------------------------------------------------------------------------
// init: acc (= d_out) = concat(user_emb, item_emb) fp32;
//       xb = same, packed bf16 (8 elems = uint4 per thread)
// ---------------------------------------------------------------------------
__global__ void lgcn_init(const float4* __restrict__ user,
                          const float4* __restrict__ item,
                          uint4* __restrict__ xb,
                          float4* __restrict__ acc) {
    int i = blockIdx.x * blockDim.x + threadIdx.x;   // chunk of 8 floats
    if (i >= N_NODES * 8) return;
    const int user_chunks = USER_NUM * 8;
    float4 f0, f1;
    if (i < user_chunks) {
        f0 = user[i * 2];
        f1 = user[i * 2 + 1];
    } else {
        f0 = item[(i - user_chunks) * 2];
        f1 = item[(i - user_chunks) * 2 + 1];
    }
    acc[i * 2]     = f0;
    acc[i * 2 + 1] = f1;
    uint4 p;
    p.x = f2bf(f0.x) | (f2bf(f0.y) << 16);
    p.y = f2bf(f0.z) | (f2bf(f0.w) << 16);
    p.z = f2bf(f1.x) | (f2bf(f1.y) << 16);
    p.w = f2bf(f1.z) | (f2bf(f1.w) << 16);
    xb[i] = p;
}

// ---------------------------------------------------------------------------
// bucket cursor init: bucket b's staging region starts at b*CB_CAP
// ---------------------------------------------------------------------------
__global__ void lgcn_bcur_init(int* __restrict__ bucket_cursor) {
    int b = blockIdx.x * blockDim.x + threadIdx.x;
    if (b < NCB) bucket_cursor[b] = b * CB_CAP;
}

// ---------------------------------------------------------------------------
// partition: per 8192-edge tile, in-LDS counting sort by coarse bucket
// (1024 rows each -> runs of ~56 edges = 448B, run-boundary overhead ~14%),
// then write staging in sorted slot order (consecutive threads -> consecutive
// addresses). Staging entry packs (rlo<<18 | col, val) -> one 8B word/edge,
// no sidecar array. NO global atomics except 147 run reservations per block.
// ---------------------------------------------------------------------------
__global__ __launch_bounds__(256) void lgcn_partition(
    const int* __restrict__ row,
    const int* __restrict__ col,
    const float* __restrict__ vals,
    int* __restrict__ bucket_cursor,  // pre-init to b*CB_CAP
    int2* __restrict__ t_cv) {
    __shared__ int hist[NCB];
    __shared__ int excl[NCB];        // exclusive start, then running cursor
    __shared__ int delta[NCB];       // global pos = delta[b] + slot
    __shared__ unsigned lslot[TILE];
    __shared__ int sscan[256];

    int tid = threadIdx.x;
    int tileStart = blockIdx.x * TILE;
    int tileCount = NNZ - tileStart;
    if (tileCount > TILE) tileCount = TILE;

    for (int b = tid; b < NCB; b += 256) hist[b] = 0;
    __syncthreads();

    // phase A: LDS bucket histogram; cache rows in regs
    int rws[EPT];
#pragma unroll
    for (int k = 0; k < EPT; ++k) {
        int le = tid + k * 256;
        int r = -1;
        if (le < tileCount) {
            r = row[tileStart + le];
            atomicAdd(&hist[r >> CB_SHIFT], 1);
        }
        rws[k] = r;
    }
    __syncthreads();

    // phase B: exclusive scan of hist (NCB=147 <= 256: one bucket per thread),
    // then reserve the global run and compute delta in the same thread.
    int h = (tid < NCB) ? hist[tid] : 0;
    sscan[tid] = h;
    __syncthreads();
    for (int off = 1; off < 256; off <<= 1) {
        int x = (tid >= off) ? sscan[tid - off] : 0;
        __syncthreads();
        sscan[tid] += x;
        __syncthreads();
    }
    if (tid < NCB) {
        int ex = sscan[tid] - h;
        excl[tid] = ex;
        int rb = h ? atomicAdd(&bucket_cursor[tid], h) : 0;
        delta[tid] = rb - ex;
    }
    __syncthreads();

    // phase C: place edges into bucket-sorted local slots
    // pack: bucket (<147) << 23 | rlo (<1024) << 13 | le (<8192)
#pragma unroll
    for (int k = 0; k < EPT; ++k) {
        int le = tid + k * 256;
        if (le < tileCount) {
            int r = rws[k];
            int b = r >> CB_SHIFT;
            int lp = atomicAdd(&excl[b], 1);
            lslot[lp] = ((unsigned)b << 23) |
                        ((unsigned)(r & (ROWS_PER_CB - 1)) << 13) |
                        (unsigned)le;
        }
    }
    __syncthreads();

    // phase D: write out in slot order -> coalesced per-run bursts
    for (int i = tid; i < tileCount; i += 256) {
        unsigned s = lslot[i];
        int b = s >> 23;
        int rlo = (s >> 13) & (ROWS_PER_CB - 1);
        int le = s & 8191;
        int e = tileStart + le;
        int gpos = delta[b] + i;
        if (gpos < (b + 1) * CB_CAP) {   // overflow guard, statistically never
            t_cv[gpos] = make_int2((rlo << 18) | col[e],
                                   __float_as_int(vals[e]));
        }
    }
}

// ---------------------------------------------------------------------------
// count: one block per coarse bucket. Reads its (L2-resident) staging
// segment, builds per-row counts in LDS (no global atomics), writes the cnt
// slice coalesced. Replaces R8's 4.8M global cnt atomics (~16B HBM each).
// ---------------------------------------------------------------------------
__global__ __launch_bounds__(256) void lgcn_count(
    const int* __restrict__ bucket_cursor,
    const int2* __restrict__ t_cv,
    int* __restrict__ cnt) {
    __shared__ int hist[ROWS_PER_CB];
    int b = blockIdx.x;
    int lo = b * ROWS_PER_CB;
    int nrows = N_NODES - lo;
    if (nrows > ROWS_PER_CB) nrows = ROWS_PER_CB;
    for (int i = threadIdx.x; i < nrows; i += 256) hist[i] = 0;
    __syncthreads();
    int base = b * CB_CAP;
    int count = bucket_cursor[b] - base;
    if (count > CB_CAP) count = CB_CAP;
    for (int e = base + threadIdx.x; e < base + count; e += 256) {
        unsigned rc = (unsigned)t_cv[e].x;
        atomicAdd(&hist[rc >> 18], 1);
    }
    __syncthreads();
    for (int i = threadIdx.x; i < nrows; i += 256) cnt[lo + i] = hist[i];
}

// ---------------------------------------------------------------------------
// scan step a: per-block sums of cnt (1024 elements / block)
// ---------------------------------------------------------------------------
__global__ void lgcn_scan_blocksums(const int* __restrict__ cnt,
                                    int* __restrict__ blockSum) {
    int b = blockIdx.x, t = threadIdx.x;
    int base = b * SCAN_ITEMS + t * 4;
    int s = 0;
#pragma unroll
    for (int k = 0; k < 4; ++k) {
        int i = base + k;
        if (i < N_NODES) s += cnt[i];
    }
    __shared__ int red[256];
    red[t] = s;
    __syncthreads();
    for (int off = 128; off > 0; off >>= 1) {
        if (t < off) red[t] += red[t + off];
        __syncthreads();
    }
    if (t == 0) blockSum[b] = red[0];
}

// ---------------------------------------------------------------------------
// scan step b: exclusive scan of block sums (single block)
// ---------------------------------------------------------------------------
__global__ void lgcn_scan_sums(const int* __restrict__ blockSum,
                               int* __restrict__ blockBase,
                               int* __restrict__ row_ptr) {
    int t = threadIdx.x;
    __shared__ int s[256];
    int v = (t < NUM_SCAN_BLOCKS) ? blockSum[t] : 0;
    s[t] = v;
    __syncthreads();
    for (int off = 1; off < 256; off <<= 1) {
        int x = (t >= off) ? s[t - off] : 0;
        __syncthreads();
        s[t] += x;
        __syncthreads();
    }
    if (t < NUM_SCAN_BLOCKS) blockBase[t] = s[t] - v;  // exclusive
    if (t == 0) row_ptr[N_NODES] = NNZ;
}

// ---------------------------------------------------------------------------
// scan step c: final exclusive scan -> row_ptr[0..N_NODES)
// ---------------------------------------------------------------------------
__global__ void lgcn_scan_final(const int* __restrict__ cnt,
                                const int* __restrict__ blockBase,
                                int* __restrict__ row_ptr) {
    int b = blockIdx.x, t = threadIdx.x;
    int base = b * SCAN_ITEMS + t * 4;
    int v[4];
    int tsum = 0;
#pragma unroll
    for (int k = 0; k < 4; ++k) {
        int i = base + k;
        v[k] = (i < N_NODES) ? cnt[i] : 0;
        tsum += v[k];
    }
    __shared__ int s[256];
    s[t] = tsum;
    __syncthreads();
    for (int off = 1; off < 256; off <<= 1) {
        int x = (t >= off) ? s[t - off] : 0;
        __syncthreads();
        s[t] += x;
        __syncthreads();
    }
    int p = blockBase[b] + (s[t] - tsum);  // exclusive prefix
#pragma unroll
    for (int k = 0; k < 4; ++k) {
        int i = base + k;
        if (i < N_NODES) row_ptr[i] = p;
        p += v[k];
    }
}

// ---------------------------------------------------------------------------
// pass 2: one block per coarse bucket. Per-row cursors in LDS; reads the
// bucket's contiguous staging segment (~272KB) and writes final CSR
// positions confined to a ~262KB window -> L2-resident, full-line writebacks.
// ---------------------------------------------------------------------------
__global__ __launch_bounds__(256) void lgcn_bucket_scatter(
    const int* __restrict__ row_ptr,
    const int* __restrict__ bucket_cursor,
    const int2* __restrict__ t_cv,
    int2* __restrict__ csr_cv) {
    __shared__ int cur[ROWS_PER_CB];
    int b = blockIdx.x;
    int lo = b * ROWS_PER_CB;
    int nrows = N_NODES - lo;
    if (nrows > ROWS_PER_CB) nrows = ROWS_PER_CB;
    for (int i = threadIdx.x; i < nrows; i += 256)
        cur[i] = row_ptr[lo + i];
    __syncthreads();
    int base = b * CB_CAP;
    int count = bucket_cursor[b] - base;
    if (count > CB_CAP) count = CB_CAP;
    for (int e = base + threadIdx.x; e < base + count; e += 256) {
        int2 cv = t_cv[e];
        int rlo = (unsigned)cv.x >> 18;
        int pos = atomicAdd(&cur[rlo], 1);
        csr_cv[pos] = make_int2(cv.x & 0x3FFFF, cv.y);
    }
}

// ---------------------------------------------------------------------------
// SpMM, bf16 gather: one wave per row. Lanes = 8 edge-subgroups x 8 chunks.
// Each lane loads 16B = 8 bf16 of x[col]; a row is 128B = ONE cache line.
// fp32 accumulate; epilogue writes y as bf16 (next layer input) and folds
// fp32 y into acc: acc = (acc + y) * scale.   (unchanged from R7/R8)
// ---------------------------------------------------------------------------
__global__ __launch_bounds__(256) void lgcn_spmm_bf16(
    const int* __restrict__ row_ptr,
    const int2* __restrict__ csr_cv,
    const uint4* __restrict__ xb,
    uint4* __restrict__ yb,
    float4* __restrict__ acc,
    float scale) {
    int gid = blockIdx.x * blockDim.x + threadIdx.x;
    int r = gid >> 6;
    if (r >= N_NODES) return;
    int lane = threadIdx.x & 63;
    int c = lane & 7;        // which 16B chunk (8 bf16) of the 64-dim row
    int sub = lane >> 3;     // edge subgroup 0..7

    int start = row_ptr[r];
    int end = row_ptr[r + 1];

    float a0[8] = {0.f, 0.f, 0.f, 0.f, 0.f, 0.f, 0.f, 0.f};
    float a1[8] = {0.f, 0.f, 0.f, 0.f, 0.f, 0.f, 0.f, 0.f};

    int e = start + sub;
    // main loop: 16 edges per wave iteration (2 per subgroup, independent)
    for (; e + 8 < end; e += 16) {
        int2 cv0 = csr_cv[e];
        int2 cv1 = csr_cv[e + 8];
        uint4 u0 = xb[cv0.x * 8 + c];
        uint4 u1 = xb[cv1.x * 8 + c];
        float v0 = __int_as_float(cv0.y);
        float v1 = __int_as_float(cv1.y);
        a0[0] += v0 * bflo(u0.x); a0[1] += v0 * bfhi(u0.x);
        a0[2] += v0 * bflo(u0.y); a0[3] += v0 * bfhi(u0.y);
        a0[4] += v0 * bflo(u0.z); a0[5] += v0 * bfhi(u0.z);
        a0[6] += v0 * bflo(u0.w); a0[7] += v0 * bfhi(u0.w);
        a1[0] += v1 * bflo(u1.x); a1[1] += v1 * bfhi(u1.x);
        a1[2] += v1 * bflo(u1.y); a1[3] += v1 * bfhi(u1.y);
        a1[4] += v1 * bflo(u1.z); a1[5] += v1 * bfhi(u1.z);
        a1[6] += v1 * bflo(u1.w); a1[7] += v1 * bfhi(u1.w);
    }
    // at most one edge left per subgroup
    if (e < end) {
        int2 cv = csr_cv[e];
        uint4 u = xb[cv.x * 8 + c];
        float v = __int_as_float(cv.y);
        a0[0] += v * bflo(u.x); a0[1] += v * bfhi(u.x);
        a0[2] += v * bflo(u.y); a0[3] += v * bfhi(u.y);
        a0[4] += v * bflo(u.z); a0[5] += v * bfhi(u.z);
        a0[6] += v * bflo(u.w); a0[7] += v * bfhi(u.w);
    }

    float a[8];
#pragma unroll
    for (int k = 0; k < 8; ++k) a[k] = a0[k] + a1[k];

    // reduce across the 8 edge subgroups (lanes differing in bits 3,4,5)
#pragma unroll
    for (int k = 0; k < 8; ++k) {
        a[k] += __shfl_xor(a[k], 8);
        a[k] += __shfl_xor(a[k], 16);
        a[k] += __shfl_xor(a[k], 32);
    }

    if (sub == 0) {
        // bf16 y for the next layer's gather
        uint4 p;
        p.x = f2bf(a[0]) | (f2bf(a[1]) << 16);
        p.y = f2bf(a[2]) | (f2bf(a[3]) << 16);
        p.z = f2bf(a[4]) | (f2bf(a[5]) << 16);
        p.w = f2bf(a[6]) | (f2bf(a[7]) << 16);
        yb[r * 8 + c] = p;
        // fp32 accumulator update (full-precision y folded in)
        int idx = r * 16 + c * 2;
        float4 o0 = acc[idx];
        float4 o1 = acc[idx + 1];
        o0.x = (o0.x + a[0]) * scale;
        o0.y = (o0.y + a[1]) * scale;
        o0.z = (o0.z + a[2]) * scale;
        o0.w = (o0.w + a[3]) * scale;
        o1.x = (o1.x + a[4]) * scale;
        o1.y = (o1.y + a[5]) * scale;
        o1.z = (o1.z + a[6]) * scale;
        o1.w = (o1.w + a[7]) * scale;
        acc[idx] = o0;
        acc[idx + 1] = o1;
    }
}

extern "C" void kernel_launch(void* const* d_in, const int* in_sizes, int n_in,
                              void* d_out, int out_size, void* d_ws, size_t ws_size,
                              hipStream_t stream) {
    const float* user_emb = (const float*)d_in[0];
    const float* item_emb = (const float*)d_in[1];
    const int*   adj_row  = (const int*)d_in[2];
    const int*   adj_col  = (const int*)d_in[3];
    const float* adj_vals = (const float*)d_in[4];
    float* out = (float*)d_out;

    // workspace layout (~99 MB):
    //   xb_a (19.2MB) | csr_cv (38.4MB) | S (union): t_cv staging (40MB)
    //   during CSR build, xb_b (19.2MB) during layers | cnt | row_ptr | small
    char* base = (char*)d_ws;
    uint4* xb_a   = (uint4*)base;                               // 19.2 MB
    int2*  csr_cv = (int2*)(base + 19200000);                   // 38.4 MB
    char*  S      = base + 57600000;
    const size_t T_ENTRIES = (size_t)NCB * CB_CAP;              // 4,998,000
    int2*  t_cv   = (int2*)S;                                   // 40.0 MB
    uint4* xb_b   = (uint4*)S;                                  // aliases t_cv
    char*  tail   = S + T_ENTRIES * 8;
    int*   cnt    = (int*)tail;                                 // 600 KB
    int*   row_ptr = cnt + N_NODES;                             // 600 KB
    int*   blockSum  = row_ptr + (N_NODES + 1);
    int*   blockBase = blockSum + 256;
    int*   bucket_cursor = blockBase + 256;                     // 147 ints

    // init: xb_a = bf16(concat(user,item)); out (acc) = fp32 concat
    {
        int threads = 256;
        int blocks = (N_NODES * 8 + threads - 1) / threads;
        lgcn_init<<<blocks, threads, 0, stream>>>(
            (const float4*)user_emb, (const float4*)item_emb,
            xb_a, (float4*)out);
    }

    // ---- CSR build ----
    lgcn_bcur_init<<<1, 256, 0, stream>>>(bucket_cursor);
    lgcn_partition<<<NTILES, 256, 0, stream>>>(
        adj_row, adj_col, adj_vals, bucket_cursor, t_cv);
    lgcn_count<<<NCB, 256, 0, stream>>>(bucket_cursor, t_cv, cnt);
    lgcn_scan_blocksums<<<NUM_SCAN_BLOCKS, 256, 0, stream>>>(cnt, blockSum);
    lgcn_scan_sums<<<1, 256, 0, stream>>>(blockSum, blockBase, row_ptr);
    lgcn_scan_final<<<NUM_SCAN_BLOCKS, 256, 0, stream>>>(cnt, blockBase, row_ptr);
    lgcn_bucket_scatter<<<NCB, 256, 0, stream>>>(
        row_ptr, bucket_cursor, t_cv, csr_cv);

    // ---- 3 propagation layers (bf16-gather SpMM, fused fp32 acc update) ----
    const int spmm_block = 256;                       // 4 waves = 4 rows / block
    const int spmm_grid = (N_NODES * 64 + spmm_block - 1) / spmm_block;
    uint4* xa = xb_a;
    uint4* xbv = xb_b;
    for (int layer = 0; layer < 3; ++layer) {
        float scale = (layer == 2) ? 0.25f : 1.0f;
        lgcn_spmm_bf16<<<spmm_grid, spmm_block, 0, stream>>>(
            row_ptr, csr_cv, xa, xbv, (float4*)out, scale);
        uint4* t = xa; xa = xbv; xbv = t;
    }
}